// Round 1
// baseline (348.324 us; speedup 1.0000x reference)
//
#include <hip/hip_runtime.h>
#include <stdint.h>

#define D 64
constexpr float NEG_SLOPE = 0.2f;
#define NPB_SHIFT 9
#define NPB 512          // nodes per bucket
#define PCHUNK 4096      // edges per partition chunk

// ce[l] = sum_d We_l[d] * ae_l[d]
__global__ void k_ce(const float* __restrict__ We1, const float* __restrict__ ae1,
                     const float* __restrict__ We2, const float* __restrict__ ae2,
                     float* __restrict__ ce){
  int lane = threadIdx.x;
  float p1 = We1[lane] * ae1[lane];
  float p2 = We2[lane] * ae2[lane];
  #pragma unroll
  for (int off = 32; off; off >>= 1){ p1 += __shfl_xor(p1, off); p2 += __shfl_xor(p2, off); }
  if (lane == 0){ ce[0] = p1; ce[1] = p2; }
}

// h = X @ W. W column in 64 VGPRs/lane. x broadcast via wave-private LDS
// tile: coalesced vector-load staging, then uniform-address ds_read_b128
// (4 MACs per DS op, broadcast = conflict-free). No SMEM, no bpermute in
// the hot loop (R8/R9/R10 post-mortems: those pipes were the bottleneck).
__global__ __launch_bounds__(256) void k_gemm_dots(
    const float* __restrict__ X, const float* __restrict__ W,
    const float* __restrict__ a_s, const float* __restrict__ a_d,
    float* __restrict__ H, float* __restrict__ asrc, float* __restrict__ adst, int n)
{
  __shared__ float sX[4 * 512];          // 2KB per wave, wave-private
  int lane = threadIdx.x & 63;
  int wv   = threadIdx.x >> 6;
  float* tile = sX + wv * 512;
  int wid  = blockIdx.x * 4 + wv;
  int nw   = gridDim.x * 4;
  float Wc[64];
  #pragma unroll
  for (int k = 0; k < 64; ++k) Wc[k] = W[k * D + lane];   // coalesced, once
  float asv = a_s[lane], adv = a_d[lane];
  int ngrp = (n + 7) >> 3;
  for (int g = wid; g < ngrp; g += nw){
    int r0 = g << 3;
    if (r0 + 8 <= n){
      const float4* Xg = (const float4*)(X + (size_t)r0 * D);
      // stage 8x64 tile: lane -> 32B, coalesced global, wave-private LDS
      float4 t0 = Xg[lane * 2], t1 = Xg[lane * 2 + 1];
      ((float4*)tile)[lane * 2]     = t0;
      ((float4*)tile)[lane * 2 + 1] = t1;
      __builtin_amdgcn_wave_barrier();   // order LDS writes before reads (same wave)
      float acc[8];
      #pragma unroll
      for (int j = 0; j < 8; ++j) acc[j] = 0.f;
      #pragma unroll
      for (int j = 0; j < 8; ++j){
        #pragma unroll
        for (int kb = 0; kb < 16; ++kb){
          float4 xv = ((const float4*)(tile + j * 64))[kb];  // uniform ds_read_b128
          acc[j] = fmaf(xv.x, Wc[kb * 4 + 0], acc[j]);
          acc[j] = fmaf(xv.y, Wc[kb * 4 + 1], acc[j]);
          acc[j] = fmaf(xv.z, Wc[kb * 4 + 2], acc[j]);
          acc[j] = fmaf(xv.w, Wc[kb * 4 + 3], acc[j]);
        }
      }
      #pragma unroll
      for (int j = 0; j < 8; ++j) H[(size_t)(r0 + j) * D + lane] = acc[j];
      #pragma unroll
      for (int j = 0; j < 8; ++j){
        float ps = acc[j] * asv, pd = acc[j] * adv;
        #pragma unroll
        for (int off = 32; off; off >>= 1){ ps += __shfl_xor(ps, off); pd += __shfl_xor(pd, off); }
        if (lane == 0){ asrc[r0 + j] = ps; adst[r0 + j] = pd; }
      }
    } else {
      for (int j = 0; r0 + j < n; ++j){
        float acc = 0.f;
        #pragma unroll
        for (int kb = 0; kb < 16; ++kb){
          float4 xv = *(const float4*)(X + (size_t)(r0 + j) * D + kb * 4);
          acc = fmaf(xv.x, Wc[kb * 4 + 0], acc);
          acc = fmaf(xv.y, Wc[kb * 4 + 1], acc);
          acc = fmaf(xv.z, Wc[kb * 4 + 2], acc);
          acc = fmaf(xv.w, Wc[kb * 4 + 3], acc);
        }
        H[(size_t)(r0 + j) * D + lane] = acc;
        float ps = acc * asv, pd = acc * adv;
        #pragma unroll
        for (int off = 32; off; off >>= 1){ ps += __shfl_xor(ps, off); pd += __shfl_xor(pd, off); }
        if (lane == 0){ asrc[r0 + j] = ps; adst[r0 + j] = pd; }
      }
    }
  }
}

// ---------------- contention-free CSR build ----------------

// per-chunk bucket histogram -> C[b*nchunk + c]  (no global atomics)
__global__ __launch_bounds__(256) void k_bhist(const int* __restrict__ dst,
    int* __restrict__ C, int nchunk, int e, int nbkt){
  __shared__ int hist[256];
  int tid = threadIdx.x, c = blockIdx.x;
  if (tid < nbkt) hist[tid] = 0;
  __syncthreads();
  int c0 = c * PCHUNK;
  #pragma unroll
  for (int k = 0; k < PCHUNK / 256; ++k){
    int i = c0 + tid + (k << 8);
    if (i < e) atomicAdd(&hist[dst[i] >> NPB_SHIFT], 1);
  }
  __syncthreads();
  if (tid < nbkt) C[tid * nchunk + c] = hist[tid];
}

// per-bucket exclusive scan of C over chunks; bucket totals (nchunk <= 512)
__global__ __launch_bounds__(512) void k_cscan(int* __restrict__ C,
    int* __restrict__ btot, int nchunk){
  __shared__ int s[512];
  int b = blockIdx.x, tid = threadIdx.x;
  int v = (tid < nchunk) ? C[b * nchunk + tid] : 0;
  s[tid] = v; __syncthreads();
  #pragma unroll
  for (int off = 1; off < 512; off <<= 1){
    int t = (tid >= off) ? s[tid - off] : 0;
    __syncthreads();
    s[tid] += t;
    __syncthreads();
  }
  if (tid < nchunk) C[b * nchunk + tid] = s[tid] - v;   // exclusive
  if (tid == 511) btot[b] = s[511];
}

// exclusive scan of bucket totals -> gbase[nbkt+1]  (nbkt <= 256)
__global__ __launch_bounds__(256) void k_bscan(const int* __restrict__ btot,
    int* __restrict__ gbase, int nbkt){
  __shared__ int s[256];
  int tid = threadIdx.x;
  int v = (tid < nbkt) ? btot[tid] : 0;
  s[tid] = v; __syncthreads();
  #pragma unroll
  for (int off = 1; off < 256; off <<= 1){
    int t = (tid >= off) ? s[tid - off] : 0;
    __syncthreads();
    s[tid] += t;
    __syncthreads();
  }
  if (tid < nbkt) gbase[tid] = s[tid] - v;
  if (tid == 255) gbase[nbkt] = s[255];
}

// partition edges into dst-buckets at precomputed offsets (zero global atomics)
__global__ __launch_bounds__(256) void k_part(const int* __restrict__ src,
    const int* __restrict__ dst, const float* __restrict__ ea,
    const int* __restrict__ gbase, const int* __restrict__ C, int nchunk,
    int2* __restrict__ staging, int e, int nbkt){
  __shared__ int base[256], cnt[256];
  int tid = threadIdx.x, c = blockIdx.x;
  if (tid < nbkt){ base[tid] = gbase[tid] + C[tid * nchunk + c]; cnt[tid] = 0; }
  __syncthreads();
  int c0 = c * PCHUNK;
  int w0[PCHUNK / 256], w1[PCHUNK / 256], bk[PCHUNK / 256];
  #pragma unroll
  for (int k = 0; k < PCHUNK / 256; ++k){
    int i = c0 + tid + (k << 8);
    bk[k] = -1;
    if (i < e){
      int d = dst[i];
      bk[k] = d >> NPB_SHIFT;
      w0[k] = src[i] | ((d & (NPB - 1)) << 17);   // src<2^17, dloc<2^9
      w1[k] = __float_as_int(ea[i]);
    }
  }
  #pragma unroll
  for (int k = 0; k < PCHUNK / 256; ++k){
    if (bk[k] >= 0){
      int pos = base[bk[k]] + atomicAdd(&cnt[bk[k]], 1);
      staging[pos] = make_int2(w0[k], w1[k]);
    }
  }
}

// one block per bucket: LDS node histogram + scan -> rowptr; permute edges
// into exact CSR positions inside the bucket's 64KB window (single CU/XCD)
__global__ __launch_bounds__(512) void k_bucket(const int* __restrict__ gbase,
    const int2* __restrict__ staging, int2* __restrict__ edges,
    int* __restrict__ rowptr, int n, int nbkt){
  __shared__ int degL[NPB], sc[NPB];
  int b = blockIdx.x, tid = threadIdx.x;
  int node0 = b << NPB_SHIFT;
  int nn = min(NPB, n - node0);
  int base = gbase[b], endj = gbase[b + 1];
  degL[tid] = 0;
  __syncthreads();
  for (int j = base + tid; j < endj; j += NPB)
    atomicAdd(&degL[staging[j].x >> 17], 1);
  __syncthreads();
  int dv = degL[tid];
  sc[tid] = dv;
  __syncthreads();
  #pragma unroll
  for (int off = 1; off < NPB; off <<= 1){
    int t = (tid >= off) ? sc[tid - off] : 0;
    __syncthreads();
    sc[tid] += t;
    __syncthreads();
  }
  int ex = sc[tid] - dv;                 // exclusive start (local)
  if (tid < nn) rowptr[node0 + tid] = base + ex;
  if (b == nbkt - 1 && tid == 0) rowptr[n] = base + sc[NPB - 1];
  __syncthreads();
  degL[tid] = ex;                        // becomes per-node cursor
  __syncthreads();
  for (int j = base + tid; j < endj; j += NPB){
    int2 w = staging[j];
    int dloc = w.x >> 17;
    int pos = base + atomicAdd(&degL[dloc], 1);
    edges[pos] = make_int2(w.x & 0x1FFFF, w.y);
  }
}

// ---------------- fused per-node softmax + aggregation ----------------
// wave per node. Softmax: lane=edge (unchanged). Aggregation: wave split
// as g=lane>>4 (edge within quad) x fi=lane&15 (float4 within row) so one
// global_load_dwordx4 fetches FOUR H-rows at 16B/lane (1KB/instr, the
// coalescing sweet spot). 4x fewer VMEM instrs / addr VALU / shuffles for
// the same bytes; final 2-step xor butterfly folds the 4 edge groups.
__global__ __launch_bounds__(256) void k_node_fused(
    const int* __restrict__ rowptr, const int2* __restrict__ edges,
    const float* __restrict__ asrc, const float* __restrict__ adst,
    const float* __restrict__ ce, int ce_idx,
    const float* __restrict__ H, const float* __restrict__ bias,
    float* __restrict__ out, int n, int relu)
{
  int v = blockIdx.x * 4 + (threadIdx.x >> 6);
  int lane = threadIdx.x & 63;
  if (v >= n) return;
  int start = rowptr[v], end = rowptr[v + 1];
  int deg = end - start;
  if (deg == 0){
    if (lane < 16){
      float4 bv4 = ((const float4*)bias)[lane];
      if (relu){
        bv4.x = fmaxf(bv4.x, 0.f); bv4.y = fmaxf(bv4.y, 0.f);
        bv4.z = fmaxf(bv4.z, 0.f); bv4.w = fmaxf(bv4.w, 0.f);
      }
      ((float4*)(out + (size_t)v * D))[lane] = bv4;
    }
    return;
  }
  float adv = adst[v];
  float cev = ce[ce_idx];
  if (deg <= 64){
    // ---- softmax: one edge per lane (numerics identical to prev version)
    int my_s = 0; float my_a = -1e30f;
    if (lane < deg){
      int2 pr = edges[start + lane];
      my_s = pr.x;
      float a = asrc[pr.x] + adv + __int_as_float(pr.y) * cev;
      my_a = a > 0.f ? a : NEG_SLOPE * a;
    }
    float m = my_a;
    #pragma unroll
    for (int off = 32; off; off >>= 1) m = fmaxf(m, __shfl_xor(m, off));
    float my_e = (lane < deg) ? __expf(my_a - m) : 0.f;   // lanes >= deg carry w=0
    float ss = my_e;
    #pragma unroll
    for (int off = 32; off; off >>= 1) ss += __shfl_xor(ss, off);
    float inv = 1.f / (ss + 1e-16f);
    // ---- aggregation: 4 rows per dwordx4 load
    int g  = lane >> 4;          // edge index within quad
    int fi = lane & 15;          // float4 index within row
    const float* Hf = H + (size_t)fi * 4;
    float4 acc  = {0.f, 0.f, 0.f, 0.f};
    float4 acc2 = {0.f, 0.f, 0.f, 0.f};
    int k = 0;
    for (; k + 16 <= deg; k += 16){
      // shfl indices <= 63 always (k <= 48 here, g <= 3)
      int s0 = __shfl(my_s, k + g),      s1 = __shfl(my_s, k + 4 + g);
      int s2 = __shfl(my_s, k + 8 + g),  s3 = __shfl(my_s, k + 12 + g);
      float w0 = __shfl(my_e, k + g),      w1 = __shfl(my_e, k + 4 + g);
      float w2 = __shfl(my_e, k + 8 + g),  w3 = __shfl(my_e, k + 12 + g);
      float4 h0 = *(const float4*)(Hf + (size_t)s0 * D);
      float4 h1 = *(const float4*)(Hf + (size_t)s1 * D);
      float4 h2 = *(const float4*)(Hf + (size_t)s2 * D);
      float4 h3 = *(const float4*)(Hf + (size_t)s3 * D);
      acc.x  = fmaf(h0.x, w0, acc.x);  acc.y  = fmaf(h0.y, w0, acc.y);
      acc.z  = fmaf(h0.z, w0, acc.z);  acc.w  = fmaf(h0.w, w0, acc.w);
      acc2.x = fmaf(h1.x, w1, acc2.x); acc2.y = fmaf(h1.y, w1, acc2.y);
      acc2.z = fmaf(h1.z, w1, acc2.z); acc2.w = fmaf(h1.w, w1, acc2.w);
      acc.x  = fmaf(h2.x, w2, acc.x);  acc.y  = fmaf(h2.y, w2, acc.y);
      acc.z  = fmaf(h2.z, w2, acc.z);  acc.w  = fmaf(h2.w, w2, acc.w);
      acc2.x = fmaf(h3.x, w3, acc2.x); acc2.y = fmaf(h3.y, w3, acc2.y);
      acc2.z = fmaf(h3.z, w3, acc2.z); acc2.w = fmaf(h3.w, w3, acc2.w);
    }
    for (; k < deg; k += 4){
      // k is a multiple of 4 and k <= 60, so k+g <= 63: lanes past deg
      // contribute w=0 (harmless H[s=their my_s] load, weight zero).
      int s0 = __shfl(my_s, k + g);
      float w0 = __shfl(my_e, k + g);
      float4 h0 = *(const float4*)(Hf + (size_t)s0 * D);
      acc.x = fmaf(h0.x, w0, acc.x); acc.y = fmaf(h0.y, w0, acc.y);
      acc.z = fmaf(h0.z, w0, acc.z); acc.w = fmaf(h0.w, w0, acc.w);
    }
    acc.x += acc2.x; acc.y += acc2.y; acc.z += acc2.z; acc.w += acc2.w;
    // fold the 4 edge-groups: butterfly over lane bits 4,5
    acc.x += __shfl_xor(acc.x, 16); acc.y += __shfl_xor(acc.y, 16);
    acc.z += __shfl_xor(acc.z, 16); acc.w += __shfl_xor(acc.w, 16);
    acc.x += __shfl_xor(acc.x, 32); acc.y += __shfl_xor(acc.y, 32);
    acc.z += __shfl_xor(acc.z, 32); acc.w += __shfl_xor(acc.w, 32);
    float4 bv4 = ((const float4*)bias)[fi];
    float4 r;
    r.x = acc.x * inv + bv4.x; r.y = acc.y * inv + bv4.y;
    r.z = acc.z * inv + bv4.z; r.w = acc.w * inv + bv4.w;
    if (relu){
      r.x = fmaxf(r.x, 0.f); r.y = fmaxf(r.y, 0.f);
      r.z = fmaxf(r.z, 0.f); r.w = fmaxf(r.w, 0.f);
    }
    if (g == 0) ((float4*)(out + (size_t)v * D))[fi] = r;
  } else {
    // rare high-degree path: lane=feature streaming (unchanged)
    float bv = bias[lane];
    float acc0 = 0.f, acc1 = 0.f, acc2 = 0.f, acc3 = 0.f;
    float m = -1e30f;
    for (int j = start + lane; j < end; j += 64){
      int2 pr = edges[j];
      float a = asrc[pr.x] + adv + __int_as_float(pr.y) * cev;
      a = a > 0.f ? a : NEG_SLOPE * a;
      m = fmaxf(m, a);
    }
    #pragma unroll
    for (int off = 32; off; off >>= 1) m = fmaxf(m, __shfl_xor(m, off));
    float ss = 0.f;
    for (int j0 = start; j0 < end; j0 += 64){
      int j = j0 + lane;
      int my_s = 0; float my_e = 0.f;
      if (j < end){
        int2 pr = edges[j];
        float a = asrc[pr.x] + adv + __int_as_float(pr.y) * cev;
        a = a > 0.f ? a : NEG_SLOPE * a;
        my_e = __expf(a - m);
        my_s = pr.x;
      }
      ss += my_e;
      int cnt = min(64, end - j0);
      int k = 0;
      for (; k + 4 <= cnt; k += 4){
        int s0 = __shfl(my_s, k+0), s1 = __shfl(my_s, k+1);
        int s2 = __shfl(my_s, k+2), s3 = __shfl(my_s, k+3);
        float w0 = __shfl(my_e, k+0), w1 = __shfl(my_e, k+1);
        float w2 = __shfl(my_e, k+2), w3 = __shfl(my_e, k+3);
        float h0 = H[(size_t)s0 * D + lane];
        float h1 = H[(size_t)s1 * D + lane];
        float h2 = H[(size_t)s2 * D + lane];
        float h3 = H[(size_t)s3 * D + lane];
        acc0 = fmaf(h0, w0, acc0); acc1 = fmaf(h1, w1, acc1);
        acc2 = fmaf(h2, w2, acc2); acc3 = fmaf(h3, w3, acc3);
      }
      for (; k < cnt; ++k){
        int s0 = __shfl(my_s, k);
        float w0 = __shfl(my_e, k);
        acc0 = fmaf(H[(size_t)s0 * D + lane], w0, acc0);
      }
    }
    #pragma unroll
    for (int off = 32; off; off >>= 1) ss += __shfl_xor(ss, off);
    float inv = 1.f / (ss + 1e-16f);
    float acc = (acc0 + acc1) + (acc2 + acc3);
    float r = acc * inv + bv;
    if (relu) r = fmaxf(r, 0.f);
    out[(size_t)v * D + lane] = r;
  }
}

extern "C" void kernel_launch(void* const* d_in, const int* in_sizes, int n_in,
                              void* d_out, int out_size, void* d_ws, size_t ws_size,
                              hipStream_t stream)
{
  const float* x    = (const float*)d_in[0];
  const int*   ei   = (const int*)d_in[1];    // integer inputs arrive as int32
  const float* ea   = (const float*)d_in[2];
  const float* W1   = (const float*)d_in[3];
  const float* We1  = (const float*)d_in[4];
  const float* as1  = (const float*)d_in[5];
  const float* ad1  = (const float*)d_in[6];
  const float* ae1  = (const float*)d_in[7];
  const float* b1   = (const float*)d_in[8];
  const float* W2   = (const float*)d_in[9];
  const float* We2  = (const float*)d_in[10];
  const float* as2  = (const float*)d_in[11];
  const float* ad2  = (const float*)d_in[12];
  const float* ae2  = (const float*)d_in[13];
  const float* b2   = (const float*)d_in[14];
  float* out = (float*)d_out;

  int n = in_sizes[0] / D;     // 100000
  int e = in_sizes[1] / 2;     // 1600000
  const int* srcp = ei;
  const int* dstp = ei + e;

  int nbkt   = (n + NPB - 1) / NPB;          // 196
  int nchunk = (e + PCHUNK - 1) / PCHUNK;    // 391  (must be <= 512)

  char* p = (char*)d_ws;
  float* buf_h   = (float*)p;  p += (size_t)n * D * 4;
  float* buf_x2  = (float*)p;  p += (size_t)n * D * 4;
  float* asrc    = (float*)p;  p += (size_t)n * 4;
  float* adst    = (float*)p;  p += (size_t)n * 4;
  int*   rowptr  = (int*)p;    p += (size_t)(n + 16) * 4;
  int*   gbase   = (int*)p;    p += (size_t)(nbkt + 4) * 4;
  int*   btot    = (int*)p;    p += (size_t)(nbkt + 4) * 4;
  int*   C       = (int*)p;    p += (size_t)nbkt * nchunk * 4;
  float* ce      = (float*)p;  p += 64;
  int2*  edges   = (int2*)p;   p += (size_t)e * 8;
  // staging aliases buf_x2: consumed by k_bucket before layer-1 writes buf_x2
  int2*  staging = (int2*)buf_x2;

  int gR = (n + 3) / 4;       // wave per node, 4 per block
  int gG = ((n + 7) / 8 + 3) / 4;   // gemm: one 8-row group per wave

  // ---- CSR build (contention-free radix partition) ----
  k_ce<<<1, 64, 0, stream>>>(We1, ae1, We2, ae2, ce);
  k_bhist<<<nchunk, 256, 0, stream>>>(dstp, C, nchunk, e, nbkt);
  k_cscan<<<nbkt, 512, 0, stream>>>(C, btot, nchunk);
  k_bscan<<<1, 256, 0, stream>>>(btot, gbase, nbkt);
  k_part<<<nchunk, 256, 0, stream>>>(srcp, dstp, ea, gbase, C, nchunk, staging, e, nbkt);
  k_bucket<<<nbkt, NPB, 0, stream>>>(gbase, staging, edges, rowptr, n, nbkt);

  // ---- layer 1 ----
  k_gemm_dots<<<gG, 256, 0, stream>>>(x, W1, as1, ad1, buf_h, asrc, adst, n);
  k_node_fused<<<gR, 256, 0, stream>>>(rowptr, edges, asrc, adst, ce, 0, buf_h, b1, buf_x2, n, 1);

  // ---- layer 2 ----
  k_gemm_dots<<<gG, 256, 0, stream>>>(buf_x2, W2, as2, ad2, buf_h, asrc, adst, n);
  k_node_fused<<<gR, 256, 0, stream>>>(rowptr, edges, asrc, adst, ce, 1, buf_h, b2, out, n, 0);
}

// Round 2
// 330.842 us; speedup vs baseline: 1.0528x; 1.0528x over previous
//
#include <hip/hip_runtime.h>
#include <stdint.h>

#define D 64
constexpr float NEG_SLOPE = 0.2f;
#define NPB_SHIFT 9
#define NPB 512          // nodes per bucket
#define PCHUNK 4096      // edges per partition chunk

// ce[l] = sum_d We_l[d] * ae_l[d]
__global__ void k_ce(const float* __restrict__ We1, const float* __restrict__ ae1,
                     const float* __restrict__ We2, const float* __restrict__ ae2,
                     float* __restrict__ ce){
  int lane = threadIdx.x;
  float p1 = We1[lane] * ae1[lane];
  float p2 = We2[lane] * ae2[lane];
  #pragma unroll
  for (int off = 32; off; off >>= 1){ p1 += __shfl_xor(p1, off); p2 += __shfl_xor(p2, off); }
  if (lane == 0){ ce[0] = p1; ce[1] = p2; }
}

// h = X @ W. W column in 64 VGPRs/lane. x broadcast via wave-private LDS
// tile: coalesced vector-load staging, then uniform-address ds_read_b128
// (4 MACs per DS op, broadcast = conflict-free).
__global__ __launch_bounds__(256) void k_gemm_dots(
    const float* __restrict__ X, const float* __restrict__ W,
    const float* __restrict__ a_s, const float* __restrict__ a_d,
    float* __restrict__ H, float* __restrict__ asrc, float* __restrict__ adst, int n)
{
  __shared__ float sX[4 * 512];          // 2KB per wave, wave-private
  int lane = threadIdx.x & 63;
  int wv   = threadIdx.x >> 6;
  float* tile = sX + wv * 512;
  int wid  = blockIdx.x * 4 + wv;
  int nw   = gridDim.x * 4;
  float Wc[64];
  #pragma unroll
  for (int k = 0; k < 64; ++k) Wc[k] = W[k * D + lane];   // coalesced, once
  float asv = a_s[lane], adv = a_d[lane];
  int ngrp = (n + 7) >> 3;
  for (int g = wid; g < ngrp; g += nw){
    int r0 = g << 3;
    if (r0 + 8 <= n){
      const float4* Xg = (const float4*)(X + (size_t)r0 * D);
      // stage 8x64 tile: lane -> 32B, coalesced global, wave-private LDS
      float4 t0 = Xg[lane * 2], t1 = Xg[lane * 2 + 1];
      ((float4*)tile)[lane * 2]     = t0;
      ((float4*)tile)[lane * 2 + 1] = t1;
      __builtin_amdgcn_wave_barrier();   // order LDS writes before reads (same wave)
      float acc[8];
      #pragma unroll
      for (int j = 0; j < 8; ++j) acc[j] = 0.f;
      #pragma unroll
      for (int j = 0; j < 8; ++j){
        #pragma unroll
        for (int kb = 0; kb < 16; ++kb){
          float4 xv = ((const float4*)(tile + j * 64))[kb];  // uniform ds_read_b128
          acc[j] = fmaf(xv.x, Wc[kb * 4 + 0], acc[j]);
          acc[j] = fmaf(xv.y, Wc[kb * 4 + 1], acc[j]);
          acc[j] = fmaf(xv.z, Wc[kb * 4 + 2], acc[j]);
          acc[j] = fmaf(xv.w, Wc[kb * 4 + 3], acc[j]);
        }
      }
      #pragma unroll
      for (int j = 0; j < 8; ++j) H[(size_t)(r0 + j) * D + lane] = acc[j];
      #pragma unroll
      for (int j = 0; j < 8; ++j){
        float ps = acc[j] * asv, pd = acc[j] * adv;
        #pragma unroll
        for (int off = 32; off; off >>= 1){ ps += __shfl_xor(ps, off); pd += __shfl_xor(pd, off); }
        if (lane == 0){ asrc[r0 + j] = ps; adst[r0 + j] = pd; }
      }
    } else {
      for (int j = 0; r0 + j < n; ++j){
        float acc = 0.f;
        #pragma unroll
        for (int kb = 0; kb < 16; ++kb){
          float4 xv = *(const float4*)(X + (size_t)(r0 + j) * D + kb * 4);
          acc = fmaf(xv.x, Wc[kb * 4 + 0], acc);
          acc = fmaf(xv.y, Wc[kb * 4 + 1], acc);
          acc = fmaf(xv.z, Wc[kb * 4 + 2], acc);
          acc = fmaf(xv.w, Wc[kb * 4 + 3], acc);
        }
        H[(size_t)(r0 + j) * D + lane] = acc;
        float ps = acc * asv, pd = acc * adv;
        #pragma unroll
        for (int off = 32; off; off >>= 1){ ps += __shfl_xor(ps, off); pd += __shfl_xor(pd, off); }
        if (lane == 0){ asrc[r0 + j] = ps; adst[r0 + j] = pd; }
      }
    }
  }
}

// ---------------- contention-free CSR build ----------------

// per-chunk bucket histogram -> C[b*nchunk + c]  (no global atomics)
__global__ __launch_bounds__(256) void k_bhist(const int* __restrict__ dst,
    int* __restrict__ C, int nchunk, int e, int nbkt){
  __shared__ int hist[256];
  int tid = threadIdx.x, c = blockIdx.x;
  if (tid < nbkt) hist[tid] = 0;
  __syncthreads();
  int c0 = c * PCHUNK;
  #pragma unroll
  for (int k = 0; k < PCHUNK / 256; ++k){
    int i = c0 + tid + (k << 8);
    if (i < e) atomicAdd(&hist[dst[i] >> NPB_SHIFT], 1);
  }
  __syncthreads();
  if (tid < nbkt) C[tid * nchunk + c] = hist[tid];
}

// per-bucket exclusive scan of C over chunks; bucket totals (nchunk <= 512)
__global__ __launch_bounds__(512) void k_cscan(int* __restrict__ C,
    int* __restrict__ btot, int nchunk){
  __shared__ int s[512];
  int b = blockIdx.x, tid = threadIdx.x;
  int v = (tid < nchunk) ? C[b * nchunk + tid] : 0;
  s[tid] = v; __syncthreads();
  #pragma unroll
  for (int off = 1; off < 512; off <<= 1){
    int t = (tid >= off) ? s[tid - off] : 0;
    __syncthreads();
    s[tid] += t;
    __syncthreads();
  }
  if (tid < nchunk) C[b * nchunk + tid] = s[tid] - v;   // exclusive
  if (tid == 511) btot[b] = s[511];
}

// exclusive scan of bucket totals -> gbase[nbkt+1]  (nbkt <= 256)
__global__ __launch_bounds__(256) void k_bscan(const int* __restrict__ btot,
    int* __restrict__ gbase, int nbkt){
  __shared__ int s[256];
  int tid = threadIdx.x;
  int v = (tid < nbkt) ? btot[tid] : 0;
  s[tid] = v; __syncthreads();
  #pragma unroll
  for (int off = 1; off < 256; off <<= 1){
    int t = (tid >= off) ? s[tid - off] : 0;
    __syncthreads();
    s[tid] += t;
    __syncthreads();
  }
  if (tid < nbkt) gbase[tid] = s[tid] - v;
  if (tid == 255) gbase[nbkt] = s[255];
}

// partition edges into dst-buckets at precomputed offsets (zero global atomics)
__global__ __launch_bounds__(256) void k_part(const int* __restrict__ src,
    const int* __restrict__ dst, const float* __restrict__ ea,
    const int* __restrict__ gbase, const int* __restrict__ C, int nchunk,
    int2* __restrict__ staging, int e, int nbkt){
  __shared__ int base[256], cnt[256];
  int tid = threadIdx.x, c = blockIdx.x;
  if (tid < nbkt){ base[tid] = gbase[tid] + C[tid * nchunk + c]; cnt[tid] = 0; }
  __syncthreads();
  int c0 = c * PCHUNK;
  int w0[PCHUNK / 256], w1[PCHUNK / 256], bk[PCHUNK / 256];
  #pragma unroll
  for (int k = 0; k < PCHUNK / 256; ++k){
    int i = c0 + tid + (k << 8);
    bk[k] = -1;
    if (i < e){
      int d = dst[i];
      bk[k] = d >> NPB_SHIFT;
      w0[k] = src[i] | ((d & (NPB - 1)) << 17);   // src<2^17, dloc<2^9
      w1[k] = __float_as_int(ea[i]);
    }
  }
  #pragma unroll
  for (int k = 0; k < PCHUNK / 256; ++k){
    if (bk[k] >= 0){
      int pos = base[bk[k]] + atomicAdd(&cnt[bk[k]], 1);
      staging[pos] = make_int2(w0[k], w1[k]);
    }
  }
}

// one block per bucket: LDS node histogram + scan -> rowptr; permute edges
// into exact CSR positions inside the bucket's 64KB window (single CU/XCD)
__global__ __launch_bounds__(512) void k_bucket(const int* __restrict__ gbase,
    const int2* __restrict__ staging, int2* __restrict__ edges,
    int* __restrict__ rowptr, int n, int nbkt){
  __shared__ int degL[NPB], sc[NPB];
  int b = blockIdx.x, tid = threadIdx.x;
  int node0 = b << NPB_SHIFT;
  int nn = min(NPB, n - node0);
  int base = gbase[b], endj = gbase[b + 1];
  degL[tid] = 0;
  __syncthreads();
  for (int j = base + tid; j < endj; j += NPB)
    atomicAdd(&degL[staging[j].x >> 17], 1);
  __syncthreads();
  int dv = degL[tid];
  sc[tid] = dv;
  __syncthreads();
  #pragma unroll
  for (int off = 1; off < NPB; off <<= 1){
    int t = (tid >= off) ? sc[tid - off] : 0;
    __syncthreads();
    sc[tid] += t;
    __syncthreads();
  }
  int ex = sc[tid] - dv;                 // exclusive start (local)
  if (tid < nn) rowptr[node0 + tid] = base + ex;
  if (b == nbkt - 1 && tid == 0) rowptr[n] = base + sc[NPB - 1];
  __syncthreads();
  degL[tid] = ex;                        // becomes per-node cursor
  __syncthreads();
  for (int j = base + tid; j < endj; j += NPB){
    int2 w = staging[j];
    int dloc = w.x >> 17;
    int pos = base + atomicAdd(&degL[dloc], 1);
    edges[pos] = make_int2(w.x & 0x1FFFF, w.y);
  }
}

// ---------------- fused per-node softmax + aggregation ----------------
// wave per node, lane=feature. R0 post-mortem: gather is LATENCY-bound
// (cutting 8->4 outstanding loads regressed 9%). So: keep 8-wide per-edge
// row gather (256B/wave contiguous), and shorten the serial chain instead:
//  - no max-subtraction pass (|alpha| ~ N(0,1.4): exp safe in fp32; ratios
//    identical) -> removes a 6-shuffle reduce, and for deg>64 an entire
//    extra edges+asrc pass
//  - normalization deferred to epilogue: weights = raw exp, acc*inv at end,
//    so H loads issue immediately; denom sum-reduce overlaps in-flight loads
//  - branchless 8-row prefetch before the sum-reduce (lanes>=deg hold
//    my_s=0/my_e=0 -> valid dup addresses, naturally-zero weights)
__global__ __launch_bounds__(256) void k_node_fused(
    const int* __restrict__ rowptr, const int2* __restrict__ edges,
    const float* __restrict__ asrc, const float* __restrict__ adst,
    const float* __restrict__ ce, int ce_idx,
    const float* __restrict__ H, const float* __restrict__ bias,
    float* __restrict__ out, int n, int relu)
{
  int v = blockIdx.x * 4 + (threadIdx.x >> 6);
  int lane = threadIdx.x & 63;
  if (v >= n) return;
  int start = rowptr[v], end = rowptr[v + 1];
  int deg = end - start;
  float bv = bias[lane];
  if (deg == 0){
    float r = relu ? fmaxf(bv, 0.f) : bv;
    out[(size_t)v * D + lane] = r;
    return;
  }
  float adv = adst[v];
  float cev = ce[ce_idx];
  float acc0 = 0.f, acc1 = 0.f, acc2 = 0.f, acc3 = 0.f;
  float inv;
  if (deg <= 64){
    int my_s = 0; float my_e = 0.f;
    if (lane < deg){
      int2 pr = edges[start + lane];
      my_s = pr.x;
      float a = asrc[pr.x] + adv + __int_as_float(pr.y) * cev;
      a = a > 0.f ? a : NEG_SLOPE * a;
      my_e = __expf(a);                 // no max-sub: |a| is O(10), safe
    }
    // ---- batch A: issue first 8 row loads NOW (branchless; lanes>=deg
    //      contribute my_s=0 -> valid row-0 address, weight will be 0)
    int sA0 = __shfl(my_s, 0), sA1 = __shfl(my_s, 1);
    int sA2 = __shfl(my_s, 2), sA3 = __shfl(my_s, 3);
    int sA4 = __shfl(my_s, 4), sA5 = __shfl(my_s, 5);
    int sA6 = __shfl(my_s, 6), sA7 = __shfl(my_s, 7);
    float hA0 = H[(size_t)sA0 * D + lane];
    float hA1 = H[(size_t)sA1 * D + lane];
    float hA2 = H[(size_t)sA2 * D + lane];
    float hA3 = H[(size_t)sA3 * D + lane];
    float hA4 = H[(size_t)sA4 * D + lane];
    float hA5 = H[(size_t)sA5 * D + lane];
    float hA6 = H[(size_t)sA6 * D + lane];
    float hA7 = H[(size_t)sA7 * D + lane];
    // ---- denominator reduction overlaps the in-flight loads
    float ss = my_e;
    #pragma unroll
    for (int off = 32; off; off >>= 1) ss += __shfl_xor(ss, off);
    inv = 1.f / (ss + 1e-16f);
    // ---- weights for batch A + FMA (loads have had ~full reduce to land)
    float wA0 = __shfl(my_e, 0), wA1 = __shfl(my_e, 1);
    float wA2 = __shfl(my_e, 2), wA3 = __shfl(my_e, 3);
    float wA4 = __shfl(my_e, 4), wA5 = __shfl(my_e, 5);
    float wA6 = __shfl(my_e, 6), wA7 = __shfl(my_e, 7);
    acc0 = fmaf(hA0, wA0, acc0); acc1 = fmaf(hA1, wA1, acc1);
    acc2 = fmaf(hA2, wA2, acc2); acc3 = fmaf(hA3, wA3, acc3);
    acc0 = fmaf(hA4, wA4, acc0); acc1 = fmaf(hA5, wA5, acc1);
    acc2 = fmaf(hA6, wA6, acc2); acc3 = fmaf(hA7, wA7, acc3);
    // ---- remaining edges: proven 8-wide in-flight gather
    int k = 8;
    for (; k + 8 <= deg; k += 8){
      int s0 = __shfl(my_s, k+0), s1 = __shfl(my_s, k+1);
      int s2 = __shfl(my_s, k+2), s3 = __shfl(my_s, k+3);
      int s4 = __shfl(my_s, k+4), s5 = __shfl(my_s, k+5);
      int s6 = __shfl(my_s, k+6), s7 = __shfl(my_s, k+7);
      float w0 = __shfl(my_e, k+0), w1 = __shfl(my_e, k+1);
      float w2 = __shfl(my_e, k+2), w3 = __shfl(my_e, k+3);
      float w4 = __shfl(my_e, k+4), w5 = __shfl(my_e, k+5);
      float w6 = __shfl(my_e, k+6), w7 = __shfl(my_e, k+7);
      float h0 = H[(size_t)s0 * D + lane];
      float h1 = H[(size_t)s1 * D + lane];
      float h2 = H[(size_t)s2 * D + lane];
      float h3 = H[(size_t)s3 * D + lane];
      float h4 = H[(size_t)s4 * D + lane];
      float h5 = H[(size_t)s5 * D + lane];
      float h6 = H[(size_t)s6 * D + lane];
      float h7 = H[(size_t)s7 * D + lane];
      acc0 = fmaf(h0, w0, acc0); acc1 = fmaf(h1, w1, acc1);
      acc2 = fmaf(h2, w2, acc2); acc3 = fmaf(h3, w3, acc3);
      acc0 = fmaf(h4, w4, acc0); acc1 = fmaf(h5, w5, acc1);
      acc2 = fmaf(h6, w6, acc2); acc3 = fmaf(h7, w7, acc3);
    }
    for (; k + 2 <= deg; k += 2){
      int s0 = __shfl(my_s, k+0), s1 = __shfl(my_s, k+1);
      float w0 = __shfl(my_e, k+0), w1 = __shfl(my_e, k+1);
      float h0 = H[(size_t)s0 * D + lane];
      float h1 = H[(size_t)s1 * D + lane];
      acc0 = fmaf(h0, w0, acc0); acc1 = fmaf(h1, w1, acc1);
    }
    if (k < deg){
      int s0 = __shfl(my_s, k);
      float w0 = __shfl(my_e, k);
      acc0 = fmaf(H[(size_t)s0 * D + lane], w0, acc0);
    }
  } else {
    // high-degree path: SINGLE pass (no max pre-pass), unnormalized weights
    float ss = 0.f;
    for (int j0 = start; j0 < end; j0 += 64){
      int j = j0 + lane;
      int my_s = 0; float my_e = 0.f;
      if (j < end){
        int2 pr = edges[j];
        float a = asrc[pr.x] + adv + __int_as_float(pr.y) * cev;
        a = a > 0.f ? a : NEG_SLOPE * a;
        my_e = __expf(a);
        my_s = pr.x;
      }
      ss += my_e;
      int cnt = min(64, end - j0);
      int k = 0;
      for (; k + 4 <= cnt; k += 4){
        int s0 = __shfl(my_s, k+0), s1 = __shfl(my_s, k+1);
        int s2 = __shfl(my_s, k+2), s3 = __shfl(my_s, k+3);
        float w0 = __shfl(my_e, k+0), w1 = __shfl(my_e, k+1);
        float w2 = __shfl(my_e, k+2), w3 = __shfl(my_e, k+3);
        float h0 = H[(size_t)s0 * D + lane];
        float h1 = H[(size_t)s1 * D + lane];
        float h2 = H[(size_t)s2 * D + lane];
        float h3 = H[(size_t)s3 * D + lane];
        acc0 = fmaf(h0, w0, acc0); acc1 = fmaf(h1, w1, acc1);
        acc2 = fmaf(h2, w2, acc2); acc3 = fmaf(h3, w3, acc3);
      }
      for (; k < cnt; ++k){
        int s0 = __shfl(my_s, k);
        float w0 = __shfl(my_e, k);
        acc0 = fmaf(H[(size_t)s0 * D + lane], w0, acc0);
      }
    }
    #pragma unroll
    for (int off = 32; off; off >>= 1) ss += __shfl_xor(ss, off);
    inv = 1.f / (ss + 1e-16f);
  }
  float acc = (acc0 + acc1) + (acc2 + acc3);
  float r = acc * inv + bv;
  if (relu) r = fmaxf(r, 0.f);
  out[(size_t)v * D + lane] = r;
}

extern "C" void kernel_launch(void* const* d_in, const int* in_sizes, int n_in,
                              void* d_out, int out_size, void* d_ws, size_t ws_size,
                              hipStream_t stream)
{
  const float* x    = (const float*)d_in[0];
  const int*   ei   = (const int*)d_in[1];    // integer inputs arrive as int32
  const float* ea   = (const float*)d_in[2];
  const float* W1   = (const float*)d_in[3];
  const float* We1  = (const float*)d_in[4];
  const float* as1  = (const float*)d_in[5];
  const float* ad1  = (const float*)d_in[6];
  const float* ae1  = (const float*)d_in[7];
  const float* b1   = (const float*)d_in[8];
  const float* W2   = (const float*)d_in[9];
  const float* We2  = (const float*)d_in[10];
  const float* as2  = (const float*)d_in[11];
  const float* ad2  = (const float*)d_in[12];
  const float* ae2  = (const float*)d_in[13];
  const float* b2   = (const float*)d_in[14];
  float* out = (float*)d_out;

  int n = in_sizes[0] / D;     // 100000
  int e = in_sizes[1] / 2;     // 1600000
  const int* srcp = ei;
  const int* dstp = ei + e;

  int nbkt   = (n + NPB - 1) / NPB;          // 196
  int nchunk = (e + PCHUNK - 1) / PCHUNK;    // 391  (must be <= 512)

  char* p = (char*)d_ws;
  float* buf_h   = (float*)p;  p += (size_t)n * D * 4;
  float* buf_x2  = (float*)p;  p += (size_t)n * D * 4;
  float* asrc    = (float*)p;  p += (size_t)n * 4;
  float* adst    = (float*)p;  p += (size_t)n * 4;
  int*   rowptr  = (int*)p;    p += (size_t)(n + 16) * 4;
  int*   gbase   = (int*)p;    p += (size_t)(nbkt + 4) * 4;
  int*   btot    = (int*)p;    p += (size_t)(nbkt + 4) * 4;
  int*   C       = (int*)p;    p += (size_t)nbkt * nchunk * 4;
  float* ce      = (float*)p;  p += 64;
  int2*  edges   = (int2*)p;   p += (size_t)e * 8;
  // staging aliases buf_x2: consumed by k_bucket before layer-1 writes buf_x2
  int2*  staging = (int2*)buf_x2;

  int gR = (n + 3) / 4;       // wave per node, 4 per block
  int gG = ((n + 7) / 8 + 3) / 4;   // gemm: one 8-row group per wave

  // ---- CSR build (contention-free radix partition) ----
  k_ce<<<1, 64, 0, stream>>>(We1, ae1, We2, ae2, ce);
  k_bhist<<<nchunk, 256, 0, stream>>>(dstp, C, nchunk, e, nbkt);
  k_cscan<<<nbkt, 512, 0, stream>>>(C, btot, nchunk);
  k_bscan<<<1, 256, 0, stream>>>(btot, gbase, nbkt);
  k_part<<<nchunk, 256, 0, stream>>>(srcp, dstp, ea, gbase, C, nchunk, staging, e, nbkt);
  k_bucket<<<nbkt, NPB, 0, stream>>>(gbase, staging, edges, rowptr, n, nbkt);

  // ---- layer 1 ----
  k_gemm_dots<<<gG, 256, 0, stream>>>(x, W1, as1, ad1, buf_h, asrc, adst, n);
  k_node_fused<<<gR, 256, 0, stream>>>(rowptr, edges, asrc, adst, ce, 0, buf_h, b1, buf_x2, n, 1);

  // ---- layer 2 ----
  k_gemm_dots<<<gG, 256, 0, stream>>>(buf_x2, W2, as2, ad2, buf_h, asrc, adst, n);
  k_node_fused<<<gR, 256, 0, stream>>>(rowptr, edges, asrc, adst, ce, 1, buf_h, b2, out, n, 0);
}

// Round 3
// 298.201 us; speedup vs baseline: 1.1681x; 1.1095x over previous
//
#include <hip/hip_runtime.h>
#include <hip/hip_fp16.h>
#include <stdint.h>

#define D 64
constexpr float NEG_SLOPE = 0.2f;
#define NPB_SHIFT 9
#define NPB 512          // nodes per bucket
#define PCHUNK 4096      // edges per partition chunk

// ce[l] = sum_d We_l[d] * ae_l[d]
__global__ void k_ce(const float* __restrict__ We1, const float* __restrict__ ae1,
                     const float* __restrict__ We2, const float* __restrict__ ae2,
                     float* __restrict__ ce){
  int lane = threadIdx.x;
  float p1 = We1[lane] * ae1[lane];
  float p2 = We2[lane] * ae2[lane];
  #pragma unroll
  for (int off = 32; off; off >>= 1){ p1 += __shfl_xor(p1, off); p2 += __shfl_xor(p2, off); }
  if (lane == 0){ ce[0] = p1; ce[1] = p2; }
}

// h = X @ W (fp32 accumulate), H stored as fp16 (gather working set halves:
// 25.6->12.8MB; per-XCD L2-miss floor = nXCD*sizeof(H) halves with it).
// asrc/adst dots computed from the fp32 accs -> no precision loss there.
__global__ __launch_bounds__(256) void k_gemm_dots(
    const float* __restrict__ X, const float* __restrict__ W,
    const float* __restrict__ a_s, const float* __restrict__ a_d,
    __half* __restrict__ H, float* __restrict__ asrc, float* __restrict__ adst, int n)
{
  __shared__ float sX[4 * 512];          // 2KB per wave, wave-private
  int lane = threadIdx.x & 63;
  int wv   = threadIdx.x >> 6;
  float* tile = sX + wv * 512;
  int wid  = blockIdx.x * 4 + wv;
  int nw   = gridDim.x * 4;
  float Wc[64];
  #pragma unroll
  for (int k = 0; k < 64; ++k) Wc[k] = W[k * D + lane];   // coalesced, once
  float asv = a_s[lane], adv = a_d[lane];
  int ngrp = (n + 7) >> 3;
  for (int g = wid; g < ngrp; g += nw){
    int r0 = g << 3;
    if (r0 + 8 <= n){
      const float4* Xg = (const float4*)(X + (size_t)r0 * D);
      // stage 8x64 tile: lane -> 32B, coalesced global, wave-private LDS
      float4 t0 = Xg[lane * 2], t1 = Xg[lane * 2 + 1];
      ((float4*)tile)[lane * 2]     = t0;
      ((float4*)tile)[lane * 2 + 1] = t1;
      __builtin_amdgcn_wave_barrier();   // order LDS writes before reads (same wave)
      float acc[8];
      #pragma unroll
      for (int j = 0; j < 8; ++j) acc[j] = 0.f;
      #pragma unroll
      for (int j = 0; j < 8; ++j){
        #pragma unroll
        for (int kb = 0; kb < 16; ++kb){
          float4 xv = ((const float4*)(tile + j * 64))[kb];  // uniform ds_read_b128
          acc[j] = fmaf(xv.x, Wc[kb * 4 + 0], acc[j]);
          acc[j] = fmaf(xv.y, Wc[kb * 4 + 1], acc[j]);
          acc[j] = fmaf(xv.z, Wc[kb * 4 + 2], acc[j]);
          acc[j] = fmaf(xv.w, Wc[kb * 4 + 3], acc[j]);
        }
      }
      #pragma unroll
      for (int j = 0; j < 8; ++j) H[(size_t)(r0 + j) * D + lane] = __float2half(acc[j]);
      #pragma unroll
      for (int j = 0; j < 8; ++j){
        float ps = acc[j] * asv, pd = acc[j] * adv;
        #pragma unroll
        for (int off = 32; off; off >>= 1){ ps += __shfl_xor(ps, off); pd += __shfl_xor(pd, off); }
        if (lane == 0){ asrc[r0 + j] = ps; adst[r0 + j] = pd; }
      }
    } else {
      for (int j = 0; r0 + j < n; ++j){
        float acc = 0.f;
        #pragma unroll
        for (int kb = 0; kb < 16; ++kb){
          float4 xv = *(const float4*)(X + (size_t)(r0 + j) * D + kb * 4);
          acc = fmaf(xv.x, Wc[kb * 4 + 0], acc);
          acc = fmaf(xv.y, Wc[kb * 4 + 1], acc);
          acc = fmaf(xv.z, Wc[kb * 4 + 2], acc);
          acc = fmaf(xv.w, Wc[kb * 4 + 3], acc);
        }
        H[(size_t)(r0 + j) * D + lane] = __float2half(acc);
        float ps = acc * asv, pd = acc * adv;
        #pragma unroll
        for (int off = 32; off; off >>= 1){ ps += __shfl_xor(ps, off); pd += __shfl_xor(pd, off); }
        if (lane == 0){ asrc[r0 + j] = ps; adst[r0 + j] = pd; }
      }
    }
  }
}

// ---------------- contention-free CSR build ----------------

// per-chunk bucket histogram -> C[b*nchunk + c]  (no global atomics)
__global__ __launch_bounds__(256) void k_bhist(const int* __restrict__ dst,
    int* __restrict__ C, int nchunk, int e, int nbkt){
  __shared__ int hist[256];
  int tid = threadIdx.x, c = blockIdx.x;
  if (tid < nbkt) hist[tid] = 0;
  __syncthreads();
  int c0 = c * PCHUNK;
  #pragma unroll
  for (int k = 0; k < PCHUNK / 256; ++k){
    int i = c0 + tid + (k << 8);
    if (i < e) atomicAdd(&hist[dst[i] >> NPB_SHIFT], 1);
  }
  __syncthreads();
  if (tid < nbkt) C[tid * nchunk + c] = hist[tid];
}

// per-bucket exclusive scan of C over chunks; bucket totals (nchunk <= 512)
__global__ __launch_bounds__(512) void k_cscan(int* __restrict__ C,
    int* __restrict__ btot, int nchunk){
  __shared__ int s[512];
  int b = blockIdx.x, tid = threadIdx.x;
  int v = (tid < nchunk) ? C[b * nchunk + tid] : 0;
  s[tid] = v; __syncthreads();
  #pragma unroll
  for (int off = 1; off < 512; off <<= 1){
    int t = (tid >= off) ? s[tid - off] : 0;
    __syncthreads();
    s[tid] += t;
    __syncthreads();
  }
  if (tid < nchunk) C[b * nchunk + tid] = s[tid] - v;   // exclusive
  if (tid == 511) btot[b] = s[511];
}

// exclusive scan of bucket totals -> gbase[nbkt+1]  (nbkt <= 256)
__global__ __launch_bounds__(256) void k_bscan(const int* __restrict__ btot,
    int* __restrict__ gbase, int nbkt){
  __shared__ int s[256];
  int tid = threadIdx.x;
  int v = (tid < nbkt) ? btot[tid] : 0;
  s[tid] = v; __syncthreads();
  #pragma unroll
  for (int off = 1; off < 256; off <<= 1){
    int t = (tid >= off) ? s[tid - off] : 0;
    __syncthreads();
    s[tid] += t;
    __syncthreads();
  }
  if (tid < nbkt) gbase[tid] = s[tid] - v;
  if (tid == 255) gbase[nbkt] = s[255];
}

// partition edges into dst-buckets at precomputed offsets (zero global atomics)
__global__ __launch_bounds__(256) void k_part(const int* __restrict__ src,
    const int* __restrict__ dst, const float* __restrict__ ea,
    const int* __restrict__ gbase, const int* __restrict__ C, int nchunk,
    int2* __restrict__ staging, int e, int nbkt){
  __shared__ int base[256], cnt[256];
  int tid = threadIdx.x, c = blockIdx.x;
  if (tid < nbkt){ base[tid] = gbase[tid] + C[tid * nchunk + c]; cnt[tid] = 0; }
  __syncthreads();
  int c0 = c * PCHUNK;
  int w0[PCHUNK / 256], w1[PCHUNK / 256], bk[PCHUNK / 256];
  #pragma unroll
  for (int k = 0; k < PCHUNK / 256; ++k){
    int i = c0 + tid + (k << 8);
    bk[k] = -1;
    if (i < e){
      int d = dst[i];
      bk[k] = d >> NPB_SHIFT;
      w0[k] = src[i] | ((d & (NPB - 1)) << 17);   // src<2^17, dloc<2^9
      w1[k] = __float_as_int(ea[i]);
    }
  }
  #pragma unroll
  for (int k = 0; k < PCHUNK / 256; ++k){
    if (bk[k] >= 0){
      int pos = base[bk[k]] + atomicAdd(&cnt[bk[k]], 1);
      staging[pos] = make_int2(w0[k], w1[k]);
    }
  }
}

// one block per bucket: LDS node histogram + scan -> rowptr; permute edges
// into exact CSR positions inside the bucket's 64KB window (single CU/XCD)
__global__ __launch_bounds__(512) void k_bucket(const int* __restrict__ gbase,
    const int2* __restrict__ staging, int2* __restrict__ edges,
    int* __restrict__ rowptr, int n, int nbkt){
  __shared__ int degL[NPB], sc[NPB];
  int b = blockIdx.x, tid = threadIdx.x;
  int node0 = b << NPB_SHIFT;
  int nn = min(NPB, n - node0);
  int base = gbase[b], endj = gbase[b + 1];
  degL[tid] = 0;
  __syncthreads();
  for (int j = base + tid; j < endj; j += NPB)
    atomicAdd(&degL[staging[j].x >> 17], 1);
  __syncthreads();
  int dv = degL[tid];
  sc[tid] = dv;
  __syncthreads();
  #pragma unroll
  for (int off = 1; off < NPB; off <<= 1){
    int t = (tid >= off) ? sc[tid - off] : 0;
    __syncthreads();
    sc[tid] += t;
    __syncthreads();
  }
  int ex = sc[tid] - dv;                 // exclusive start (local)
  if (tid < nn) rowptr[node0 + tid] = base + ex;
  if (b == nbkt - 1 && tid == 0) rowptr[n] = base + sc[NPB - 1];
  __syncthreads();
  degL[tid] = ex;                        // becomes per-node cursor
  __syncthreads();
  for (int j = base + tid; j < endj; j += NPB){
    int2 w = staging[j];
    int dloc = w.x >> 17;
    int pos = base + atomicAdd(&degL[dloc], 1);
    edges[pos] = make_int2(w.x & 0x1FFFF, w.y);
  }
}

// ---------------- fused per-node softmax + aggregation ----------------
// wave per node. H is fp16: a row is 128B, so ONE global_load_dword
// (4B/lane) fetches TWO rows: lanes 0-31 = even edge of a pair, lanes
// 32-63 = odd edge; lane owns feature pair {2*(lane&31), +1}. 8 loads in
// flight per block (R0/R1 lesson: never reduce in-flight instr count) now
// carry 16 rows. Shuffle count per edge halves. Final shfl_xor(32) folds
// even/odd partials; lanes 0-31 store float2. Deferred normalization and
// loads-before-denom-reduce overlap kept from R2. Lanes >= deg carry
// my_s=0/my_e=0 (branchless padding); tail clamps shuffle idx to 63
// (weight there provably 0 whenever the tail executes, since deg<64).
__global__ __launch_bounds__(256) void k_node_fused(
    const int* __restrict__ rowptr, const int2* __restrict__ edges,
    const float* __restrict__ asrc, const float* __restrict__ adst,
    const float* __restrict__ ce, int ce_idx,
    const __half* __restrict__ H, const float* __restrict__ bias,
    float* __restrict__ out, int n, int relu)
{
  int v = blockIdx.x * 4 + (threadIdx.x >> 6);
  int lane = threadIdx.x & 63;
  if (v >= n) return;
  int start = rowptr[v], end = rowptr[v + 1];
  int deg = end - start;
  if (deg == 0){
    float bv = bias[lane];
    float r = relu ? fmaxf(bv, 0.f) : bv;
    out[(size_t)v * D + lane] = r;
    return;
  }
  float adv = adst[v];
  float cev = ce[ce_idx];
  if (deg <= 64){
    int my_s = 0; float my_e = 0.f;
    if (lane < deg){
      int2 pr = edges[start + lane];
      my_s = pr.x;
      float a = asrc[pr.x] + adv + __int_as_float(pr.y) * cev;
      a = a > 0.f ? a : NEG_SLOPE * a;
      my_e = __expf(a);                 // no max-sub: |a| is O(10), safe
    }
    int half = lane >> 5;               // 0: even edge of pair, 1: odd
    int fp   = lane & 31;               // feature-pair index
    const __half2* H2 = (const __half2*)H;   // 32 half2 per row
    int sP[8]; float wP[8]; __half2 uP[8];
    // ---- block 0 (edges 0..15): issue loads NOW, before denom reduce
    #pragma unroll
    for (int p = 0; p < 8; ++p) sP[p] = __shfl(my_s, 2 * p + half);
    #pragma unroll
    for (int p = 0; p < 8; ++p) uP[p] = H2[(size_t)sP[p] * 32 + fp];
    // ---- denominator reduction overlaps the in-flight loads
    float ss = my_e;
    #pragma unroll
    for (int off = 32; off; off >>= 1) ss += __shfl_xor(ss, off);
    float inv = 1.f / (ss + 1e-16f);
    // ---- block 0 weights + fma
    #pragma unroll
    for (int p = 0; p < 8; ++p) wP[p] = __shfl(my_e, 2 * p + half);
    float accx = 0.f, accy = 0.f;
    #pragma unroll
    for (int p = 0; p < 8; ++p){
      float2 hv = __half22float2(uP[p]);
      accx = fmaf(hv.x, wP[p], accx);
      accy = fmaf(hv.y, wP[p], accy);
    }
    // ---- remaining blocks of 16 edges (8 pair-loads each)
    for (int k = 16; k < deg; k += 16){
      #pragma unroll
      for (int p = 0; p < 8; ++p){
        int ix = k + 2 * p + half; ix = ix > 63 ? 63 : ix;
        sP[p] = __shfl(my_s, ix);
      }
      #pragma unroll
      for (int p = 0; p < 8; ++p) uP[p] = H2[(size_t)sP[p] * 32 + fp];
      #pragma unroll
      for (int p = 0; p < 8; ++p){
        int ix = k + 2 * p + half; ix = ix > 63 ? 63 : ix;
        wP[p] = __shfl(my_e, ix);
      }
      #pragma unroll
      for (int p = 0; p < 8; ++p){
        float2 hv = __half22float2(uP[p]);
        accx = fmaf(hv.x, wP[p], accx);
        accy = fmaf(hv.y, wP[p], accy);
      }
    }
    // ---- fold even/odd halves; lanes 0-31 hold full feature-pair sums
    accx += __shfl_xor(accx, 32);
    accy += __shfl_xor(accy, 32);
    if (lane < 32){
      float2 bv2 = ((const float2*)bias)[fp];
      float2 r;
      r.x = accx * inv + bv2.x;
      r.y = accy * inv + bv2.y;
      if (relu){ r.x = fmaxf(r.x, 0.f); r.y = fmaxf(r.y, 0.f); }
      ((float2*)(out + (size_t)v * D))[fp] = r;
    }
  } else {
    // rare high-degree path: lane=feature, single pass, fp16 loads
    float bv = bias[lane];
    float acc0 = 0.f, acc1 = 0.f, acc2 = 0.f, acc3 = 0.f;
    float ss = 0.f;
    for (int j0 = start; j0 < end; j0 += 64){
      int j = j0 + lane;
      int my_s = 0; float my_e = 0.f;
      if (j < end){
        int2 pr = edges[j];
        float a = asrc[pr.x] + adv + __int_as_float(pr.y) * cev;
        a = a > 0.f ? a : NEG_SLOPE * a;
        my_e = __expf(a);
        my_s = pr.x;
      }
      ss += my_e;
      int cnt = min(64, end - j0);
      int k = 0;
      for (; k + 4 <= cnt; k += 4){
        int s0 = __shfl(my_s, k+0), s1 = __shfl(my_s, k+1);
        int s2 = __shfl(my_s, k+2), s3 = __shfl(my_s, k+3);
        float w0 = __shfl(my_e, k+0), w1 = __shfl(my_e, k+1);
        float w2 = __shfl(my_e, k+2), w3 = __shfl(my_e, k+3);
        float h0 = __half2float(H[(size_t)s0 * D + lane]);
        float h1 = __half2float(H[(size_t)s1 * D + lane]);
        float h2 = __half2float(H[(size_t)s2 * D + lane]);
        float h3 = __half2float(H[(size_t)s3 * D + lane]);
        acc0 = fmaf(h0, w0, acc0); acc1 = fmaf(h1, w1, acc1);
        acc2 = fmaf(h2, w2, acc2); acc3 = fmaf(h3, w3, acc3);
      }
      for (; k < cnt; ++k){
        int s0 = __shfl(my_s, k);
        float w0 = __shfl(my_e, k);
        acc0 = fmaf(__half2float(H[(size_t)s0 * D + lane]), w0, acc0);
      }
    }
    #pragma unroll
    for (int off = 32; off; off >>= 1) ss += __shfl_xor(ss, off);
    float inv = 1.f / (ss + 1e-16f);
    float acc = (acc0 + acc1) + (acc2 + acc3);
    float r = acc * inv + bv;
    if (relu) r = fmaxf(r, 0.f);
    out[(size_t)v * D + lane] = r;
  }
}

extern "C" void kernel_launch(void* const* d_in, const int* in_sizes, int n_in,
                              void* d_out, int out_size, void* d_ws, size_t ws_size,
                              hipStream_t stream)
{
  const float* x    = (const float*)d_in[0];
  const int*   ei   = (const int*)d_in[1];    // integer inputs arrive as int32
  const float* ea   = (const float*)d_in[2];
  const float* W1   = (const float*)d_in[3];
  const float* We1  = (const float*)d_in[4];
  const float* as1  = (const float*)d_in[5];
  const float* ad1  = (const float*)d_in[6];
  const float* ae1  = (const float*)d_in[7];
  const float* b1   = (const float*)d_in[8];
  const float* W2   = (const float*)d_in[9];
  const float* We2  = (const float*)d_in[10];
  const float* as2  = (const float*)d_in[11];
  const float* ad2  = (const float*)d_in[12];
  const float* ae2  = (const float*)d_in[13];
  const float* b2   = (const float*)d_in[14];
  float* out = (float*)d_out;

  int n = in_sizes[0] / D;     // 100000
  int e = in_sizes[1] / 2;     // 1600000
  const int* srcp = ei;
  const int* dstp = ei + e;

  int nbkt   = (n + NPB - 1) / NPB;          // 196
  int nchunk = (e + PCHUNK - 1) / PCHUNK;    // 391  (must be <= 512)

  char* p = (char*)d_ws;
  __half* buf_h  = (__half*)p; p += (size_t)n * D * 2;   // fp16 H
  float* buf_x2  = (float*)p;  p += (size_t)n * D * 4;
  float* asrc    = (float*)p;  p += (size_t)n * 4;
  float* adst    = (float*)p;  p += (size_t)n * 4;
  int*   rowptr  = (int*)p;    p += (size_t)(n + 16) * 4;
  int*   gbase   = (int*)p;    p += (size_t)(nbkt + 4) * 4;
  int*   btot    = (int*)p;    p += (size_t)(nbkt + 4) * 4;
  int*   C       = (int*)p;    p += (size_t)nbkt * nchunk * 4;
  float* ce      = (float*)p;  p += 64;
  int2*  edges   = (int2*)p;   p += (size_t)e * 8;
  // staging aliases buf_x2: consumed by k_bucket before layer-1 writes buf_x2
  int2*  staging = (int2*)buf_x2;

  int gR = (n + 3) / 4;       // wave per node, 4 per block
  int gG = ((n + 7) / 8 + 3) / 4;   // gemm: one 8-row group per wave

  // ---- CSR build (contention-free radix partition) ----
  k_ce<<<1, 64, 0, stream>>>(We1, ae1, We2, ae2, ce);
  k_bhist<<<nchunk, 256, 0, stream>>>(dstp, C, nchunk, e, nbkt);
  k_cscan<<<nbkt, 512, 0, stream>>>(C, btot, nchunk);
  k_bscan<<<1, 256, 0, stream>>>(btot, gbase, nbkt);
  k_part<<<nchunk, 256, 0, stream>>>(srcp, dstp, ea, gbase, C, nchunk, staging, e, nbkt);
  k_bucket<<<nbkt, NPB, 0, stream>>>(gbase, staging, edges, rowptr, n, nbkt);

  // ---- layer 1 ----
  k_gemm_dots<<<gG, 256, 0, stream>>>(x, W1, as1, ad1, buf_h, asrc, adst, n);
  k_node_fused<<<gR, 256, 0, stream>>>(rowptr, edges, asrc, adst, ce, 0, buf_h, b1, buf_x2, n, 1);

  // ---- layer 2 ----
  k_gemm_dots<<<gG, 256, 0, stream>>>(buf_x2, W2, as2, ad2, buf_h, asrc, adst, n);
  k_node_fused<<<gR, 256, 0, stream>>>(rowptr, edges, asrc, adst, ce, 1, buf_h, b2, out, n, 0);
}

// Round 4
// 281.474 us; speedup vs baseline: 1.2375x; 1.0594x over previous
//
#include <hip/hip_runtime.h>
#include <hip/hip_fp16.h>
#include <stdint.h>

#define D 64
constexpr float NEG_SLOPE = 0.2f;
#define NPB_SHIFT 9
#define NPB 512          // nodes per bucket
#define PCHUNK 4096      // edges per partition chunk

// ce[l] = sum_d We_l[d] * ae_l[d]
__global__ void k_ce(const float* __restrict__ We1, const float* __restrict__ ae1,
                     const float* __restrict__ We2, const float* __restrict__ ae2,
                     float* __restrict__ ce){
  int lane = threadIdx.x;
  float p1 = We1[lane] * ae1[lane];
  float p2 = We2[lane] * ae2[lane];
  #pragma unroll
  for (int off = 32; off; off >>= 1){ p1 += __shfl_xor(p1, off); p2 += __shfl_xor(p2, off); }
  if (lane == 0){ ce[0] = p1; ce[1] = p2; }
}

// h = X @ W (fp32 accumulate), H stored as fp16 (gather working set halves:
// 25.6->12.8MB; per-XCD L2-miss floor = nXCD*sizeof(H) halves with it).
// asrc/adst dots computed from the fp32 accs -> no precision loss there.
__global__ __launch_bounds__(256) void k_gemm_dots(
    const float* __restrict__ X, const float* __restrict__ W,
    const float* __restrict__ a_s, const float* __restrict__ a_d,
    __half* __restrict__ H, float* __restrict__ asrc, float* __restrict__ adst, int n)
{
  __shared__ float sX[4 * 512];          // 2KB per wave, wave-private
  int lane = threadIdx.x & 63;
  int wv   = threadIdx.x >> 6;
  float* tile = sX + wv * 512;
  int wid  = blockIdx.x * 4 + wv;
  int nw   = gridDim.x * 4;
  float Wc[64];
  #pragma unroll
  for (int k = 0; k < 64; ++k) Wc[k] = W[k * D + lane];   // coalesced, once
  float asv = a_s[lane], adv = a_d[lane];
  int ngrp = (n + 7) >> 3;
  for (int g = wid; g < ngrp; g += nw){
    int r0 = g << 3;
    if (r0 + 8 <= n){
      const float4* Xg = (const float4*)(X + (size_t)r0 * D);
      // stage 8x64 tile: lane -> 32B, coalesced global, wave-private LDS
      float4 t0 = Xg[lane * 2], t1 = Xg[lane * 2 + 1];
      ((float4*)tile)[lane * 2]     = t0;
      ((float4*)tile)[lane * 2 + 1] = t1;
      __builtin_amdgcn_wave_barrier();   // order LDS writes before reads (same wave)
      float acc[8];
      #pragma unroll
      for (int j = 0; j < 8; ++j) acc[j] = 0.f;
      #pragma unroll
      for (int j = 0; j < 8; ++j){
        #pragma unroll
        for (int kb = 0; kb < 16; ++kb){
          float4 xv = ((const float4*)(tile + j * 64))[kb];  // uniform ds_read_b128
          acc[j] = fmaf(xv.x, Wc[kb * 4 + 0], acc[j]);
          acc[j] = fmaf(xv.y, Wc[kb * 4 + 1], acc[j]);
          acc[j] = fmaf(xv.z, Wc[kb * 4 + 2], acc[j]);
          acc[j] = fmaf(xv.w, Wc[kb * 4 + 3], acc[j]);
        }
      }
      #pragma unroll
      for (int j = 0; j < 8; ++j) H[(size_t)(r0 + j) * D + lane] = __float2half(acc[j]);
      #pragma unroll
      for (int j = 0; j < 8; ++j){
        float ps = acc[j] * asv, pd = acc[j] * adv;
        #pragma unroll
        for (int off = 32; off; off >>= 1){ ps += __shfl_xor(ps, off); pd += __shfl_xor(pd, off); }
        if (lane == 0){ asrc[r0 + j] = ps; adst[r0 + j] = pd; }
      }
    } else {
      for (int j = 0; r0 + j < n; ++j){
        float acc = 0.f;
        #pragma unroll
        for (int kb = 0; kb < 16; ++kb){
          float4 xv = *(const float4*)(X + (size_t)(r0 + j) * D + kb * 4);
          acc = fmaf(xv.x, Wc[kb * 4 + 0], acc);
          acc = fmaf(xv.y, Wc[kb * 4 + 1], acc);
          acc = fmaf(xv.z, Wc[kb * 4 + 2], acc);
          acc = fmaf(xv.w, Wc[kb * 4 + 3], acc);
        }
        H[(size_t)(r0 + j) * D + lane] = __float2half(acc);
        float ps = acc * asv, pd = acc * adv;
        #pragma unroll
        for (int off = 32; off; off >>= 1){ ps += __shfl_xor(ps, off); pd += __shfl_xor(pd, off); }
        if (lane == 0){ asrc[r0 + j] = ps; adst[r0 + j] = pd; }
      }
    }
  }
}

// ---------------- contention-free CSR build ----------------

// per-chunk bucket histogram -> C[b*nchunk + c]  (no global atomics)
__global__ __launch_bounds__(256) void k_bhist(const int* __restrict__ dst,
    int* __restrict__ C, int nchunk, int e, int nbkt){
  __shared__ int hist[256];
  int tid = threadIdx.x, c = blockIdx.x;
  if (tid < nbkt) hist[tid] = 0;
  __syncthreads();
  int c0 = c * PCHUNK;
  #pragma unroll
  for (int k = 0; k < PCHUNK / 256; ++k){
    int i = c0 + tid + (k << 8);
    if (i < e) atomicAdd(&hist[dst[i] >> NPB_SHIFT], 1);
  }
  __syncthreads();
  if (tid < nbkt) C[tid * nchunk + c] = hist[tid];
}

// per-bucket exclusive scan of C over chunks; bucket totals (nchunk <= 512)
__global__ __launch_bounds__(512) void k_cscan(int* __restrict__ C,
    int* __restrict__ btot, int nchunk){
  __shared__ int s[512];
  int b = blockIdx.x, tid = threadIdx.x;
  int v = (tid < nchunk) ? C[b * nchunk + tid] : 0;
  s[tid] = v; __syncthreads();
  #pragma unroll
  for (int off = 1; off < 512; off <<= 1){
    int t = (tid >= off) ? s[tid - off] : 0;
    __syncthreads();
    s[tid] += t;
    __syncthreads();
  }
  if (tid < nchunk) C[b * nchunk + tid] = s[tid] - v;   // exclusive
  if (tid == 511) btot[b] = s[511];
}

// exclusive scan of bucket totals -> gbase[nbkt+1]  (nbkt <= 256)
__global__ __launch_bounds__(256) void k_bscan(const int* __restrict__ btot,
    int* __restrict__ gbase, int nbkt){
  __shared__ int s[256];
  int tid = threadIdx.x;
  int v = (tid < nbkt) ? btot[tid] : 0;
  s[tid] = v; __syncthreads();
  #pragma unroll
  for (int off = 1; off < 256; off <<= 1){
    int t = (tid >= off) ? s[tid - off] : 0;
    __syncthreads();
    s[tid] += t;
    __syncthreads();
  }
  if (tid < nbkt) gbase[tid] = s[tid] - v;
  if (tid == 255) gbase[nbkt] = s[255];
}

// partition edges into dst-buckets at precomputed offsets (zero global atomics)
__global__ __launch_bounds__(256) void k_part(const int* __restrict__ src,
    const int* __restrict__ dst, const float* __restrict__ ea,
    const int* __restrict__ gbase, const int* __restrict__ C, int nchunk,
    int2* __restrict__ staging, int e, int nbkt){
  __shared__ int base[256], cnt[256];
  int tid = threadIdx.x, c = blockIdx.x;
  if (tid < nbkt){ base[tid] = gbase[tid] + C[tid * nchunk + c]; cnt[tid] = 0; }
  __syncthreads();
  int c0 = c * PCHUNK;
  int w0[PCHUNK / 256], w1[PCHUNK / 256], bk[PCHUNK / 256];
  #pragma unroll
  for (int k = 0; k < PCHUNK / 256; ++k){
    int i = c0 + tid + (k << 8);
    bk[k] = -1;
    if (i < e){
      int d = dst[i];
      bk[k] = d >> NPB_SHIFT;
      w0[k] = src[i] | ((d & (NPB - 1)) << 17);   // src<2^17, dloc<2^9
      w1[k] = __float_as_int(ea[i]);
    }
  }
  #pragma unroll
  for (int k = 0; k < PCHUNK / 256; ++k){
    if (bk[k] >= 0){
      int pos = base[bk[k]] + atomicAdd(&cnt[bk[k]], 1);
      staging[pos] = make_int2(w0[k], w1[k]);
    }
  }
}

// one block per bucket: LDS node histogram + scan -> rowptr; permute edges
// into exact CSR positions inside the bucket's 64KB window (single CU/XCD)
__global__ __launch_bounds__(512) void k_bucket(const int* __restrict__ gbase,
    const int2* __restrict__ staging, int2* __restrict__ edges,
    int* __restrict__ rowptr, int n, int nbkt){
  __shared__ int degL[NPB], sc[NPB];
  int b = blockIdx.x, tid = threadIdx.x;
  int node0 = b << NPB_SHIFT;
  int nn = min(NPB, n - node0);
  int base = gbase[b], endj = gbase[b + 1];
  degL[tid] = 0;
  __syncthreads();
  for (int j = base + tid; j < endj; j += NPB)
    atomicAdd(&degL[staging[j].x >> 17], 1);
  __syncthreads();
  int dv = degL[tid];
  sc[tid] = dv;
  __syncthreads();
  #pragma unroll
  for (int off = 1; off < NPB; off <<= 1){
    int t = (tid >= off) ? sc[tid - off] : 0;
    __syncthreads();
    sc[tid] += t;
    __syncthreads();
  }
  int ex = sc[tid] - dv;                 // exclusive start (local)
  if (tid < nn) rowptr[node0 + tid] = base + ex;
  if (b == nbkt - 1 && tid == 0) rowptr[n] = base + sc[NPB - 1];
  __syncthreads();
  degL[tid] = ex;                        // becomes per-node cursor
  __syncthreads();
  for (int j = base + tid; j < endj; j += NPB){
    int2 w = staging[j];
    int dloc = w.x >> 17;
    int pos = base + atomicAdd(&degL[dloc], 1);
    edges[pos] = make_int2(w.x & 0x1FFFF, w.y);
  }
}

// ---------------- fused per-node softmax + aggregation ----------------
// TWO nodes per wave: half h = lane>>5 owns node vbase+h (deg<=32 fast
// path, covers 99.98% of Poisson(16) nodes). Two INDEPENDENT dependency
// chains (rowptr->edges->asrc->H) per wave double latency hiding at
// constant occupancy; wave count halves (prologue/reduce/epilogue shared).
// Within a half the proven pair scheme: sub=li>>4 picks edge of a pair,
// fq=li&15 owns feature quad; uint2 load = 8B/lane -> each wave-level load
// carries 4 rows, 8 loads in flight = 16 rows (in-flight volume preserved,
// R0 lesson). Denominator reduce is width-32 (5 shuffles). deg==0 falls
// out naturally (ss=0 -> acc=0 -> bias). Waves where either node has
// deg>32 (~20 of 100k) take the old full-wave path per node sequentially.
__global__ __launch_bounds__(256) void k_node_fused(
    const int* __restrict__ rowptr, const int2* __restrict__ edges,
    const float* __restrict__ asrc, const float* __restrict__ adst,
    const float* __restrict__ ce, int ce_idx,
    const __half* __restrict__ H, const float* __restrict__ bias,
    float* __restrict__ out, int n, int relu)
{
  int lane = threadIdx.x & 63;
  int wv   = threadIdx.x >> 6;
  int vbase = (blockIdx.x * 4 + wv) * 2;
  if (vbase >= n) return;
  int h  = lane >> 5;                  // which node this half owns
  int li = lane & 31;
  int v  = vbase + h;
  bool vok = v < n;
  int start = 0, end = 0;
  if (vok){ start = rowptr[v]; end = rowptr[v + 1]; }
  int deg = end - start;
  int degmax = max(deg, __shfl_xor(deg, 32));   // wave-uniform
  float cev = ce[ce_idx];

  if (degmax <= 32){
    // ---- per-half logits+exp: one edge per lane of the half
    int my_s = 0; float my_e = 0.f;
    if (li < deg){                      // vok==false -> deg==0 -> no lanes
      int2 pr = edges[start + li];
      my_s = pr.x;
      float a = asrc[pr.x] + adst[v] + __int_as_float(pr.y) * cev;
      a = a > 0.f ? a : NEG_SLOPE * a;
      my_e = __expf(a);                 // no max-sub: |a| is O(10), safe
    }
    int sub = li >> 4;                  // which edge of the pair
    int fq  = li & 15;                  // feature quad: features 4fq..4fq+3
    const uint2* H2 = (const uint2*)H;  // one row = 16 uint2
    int eb = h * 32 + sub;              // shuffle base (stay within half)
    int sP[8]; float wP[8]; uint2 uP[8];
    // ---- batch 0 (edges 0..15 per half): issue loads before denom reduce
    #pragma unroll
    for (int p = 0; p < 8; ++p) sP[p] = __shfl(my_s, eb + 2 * p);
    #pragma unroll
    for (int p = 0; p < 8; ++p) uP[p] = H2[(size_t)sP[p] * 16 + fq];
    // ---- width-32 denominator reduce overlaps the in-flight loads
    float ss = my_e;
    #pragma unroll
    for (int off = 16; off; off >>= 1) ss += __shfl_xor(ss, off);
    float inv = 1.f / (ss + 1e-16f);
    #pragma unroll
    for (int p = 0; p < 8; ++p) wP[p] = __shfl(my_e, eb + 2 * p);
    float a0 = 0.f, a1 = 0.f, a2 = 0.f, a3 = 0.f;
    #pragma unroll
    for (int p = 0; p < 8; ++p){
      __half2 q0 = *(const __half2*)&uP[p].x;
      __half2 q1 = *(const __half2*)&uP[p].y;
      float2 f0 = __half22float2(q0);
      float2 f1 = __half22float2(q1);
      a0 = fmaf(f0.x, wP[p], a0);
      a1 = fmaf(f0.y, wP[p], a1);
      a2 = fmaf(f1.x, wP[p], a2);
      a3 = fmaf(f1.y, wP[p], a3);
    }
    // ---- batch 1 (edges 16..31 per half), wave-uniform condition
    if (degmax > 16){
      #pragma unroll
      for (int p = 0; p < 8; ++p) sP[p] = __shfl(my_s, eb + 16 + 2 * p);
      #pragma unroll
      for (int p = 0; p < 8; ++p) uP[p] = H2[(size_t)sP[p] * 16 + fq];
      #pragma unroll
      for (int p = 0; p < 8; ++p) wP[p] = __shfl(my_e, eb + 16 + 2 * p);
      #pragma unroll
      for (int p = 0; p < 8; ++p){
        __half2 q0 = *(const __half2*)&uP[p].x;
        __half2 q1 = *(const __half2*)&uP[p].y;
        float2 f0 = __half22float2(q0);
        float2 f1 = __half22float2(q1);
        a0 = fmaf(f0.x, wP[p], a0);
        a1 = fmaf(f0.y, wP[p], a1);
        a2 = fmaf(f1.x, wP[p], a2);
        a3 = fmaf(f1.y, wP[p], a3);
      }
    }
    // ---- fold sub pair; lanes li<16 hold full 4-feature sums
    a0 += __shfl_xor(a0, 16);
    a1 += __shfl_xor(a1, 16);
    a2 += __shfl_xor(a2, 16);
    a3 += __shfl_xor(a3, 16);
    if (vok && li < 16){
      float4 bv = ((const float4*)bias)[li];
      float4 r;
      r.x = a0 * inv + bv.x;
      r.y = a1 * inv + bv.y;
      r.z = a2 * inv + bv.z;
      r.w = a3 * inv + bv.w;
      if (relu){
        r.x = fmaxf(r.x, 0.f); r.y = fmaxf(r.y, 0.f);
        r.z = fmaxf(r.z, 0.f); r.w = fmaxf(r.w, 0.f);
      }
      ((float4*)(out + (size_t)v * D))[li] = r;
    }
  } else {
    // ---- rare path (~20 waves): whole wave per node, sequentially
    for (int t = 0; t < 2; ++t){
      int vv = vbase + t;
      if (vv >= n) break;
      int st = rowptr[vv], en = rowptr[vv + 1];
      int dg = en - st;
      if (dg == 0){
        float bv = bias[lane];
        float r = relu ? fmaxf(bv, 0.f) : bv;
        out[(size_t)vv * D + lane] = r;
        continue;
      }
      float adv = adst[vv];
      if (dg <= 64){
        int my_s = 0; float my_e = 0.f;
        if (lane < dg){
          int2 pr = edges[st + lane];
          my_s = pr.x;
          float a = asrc[pr.x] + adv + __int_as_float(pr.y) * cev;
          a = a > 0.f ? a : NEG_SLOPE * a;
          my_e = __expf(a);
        }
        int hf = lane >> 5;             // even/odd edge of pair
        int fp = lane & 31;             // feature-pair index
        const __half2* Hp = (const __half2*)H;   // 32 half2 per row
        float ss = my_e;
        #pragma unroll
        for (int off = 32; off; off >>= 1) ss += __shfl_xor(ss, off);
        float inv = 1.f / (ss + 1e-16f);
        float accx = 0.f, accy = 0.f;
        for (int k = 0; k < dg; k += 16){
          #pragma unroll
          for (int p = 0; p < 8; ++p){
            int ix = k + 2 * p + hf; ix = ix > 63 ? 63 : ix;
            int s0 = __shfl(my_s, ix);
            float w0 = __shfl(my_e, ix);
            float2 hv = __half22float2(Hp[(size_t)s0 * 32 + fp]);
            accx = fmaf(hv.x, w0, accx);
            accy = fmaf(hv.y, w0, accy);
          }
        }
        accx += __shfl_xor(accx, 32);
        accy += __shfl_xor(accy, 32);
        if (lane < 32){
          float2 bv2 = ((const float2*)bias)[fp];
          float2 r;
          r.x = accx * inv + bv2.x;
          r.y = accy * inv + bv2.y;
          if (relu){ r.x = fmaxf(r.x, 0.f); r.y = fmaxf(r.y, 0.f); }
          ((float2*)(out + (size_t)vv * D))[fp] = r;
        }
      } else {
        // deg > 64: lane=feature streaming
        float bv = bias[lane];
        float c0 = 0.f, c1 = 0.f, c2 = 0.f, c3 = 0.f;
        float ss = 0.f;
        for (int j0 = st; j0 < en; j0 += 64){
          int j = j0 + lane;
          int my_s = 0; float my_e = 0.f;
          if (j < en){
            int2 pr = edges[j];
            float a = asrc[pr.x] + adv + __int_as_float(pr.y) * cev;
            a = a > 0.f ? a : NEG_SLOPE * a;
            my_e = __expf(a);
            my_s = pr.x;
          }
          ss += my_e;
          int cnt = min(64, en - j0);
          int k = 0;
          for (; k + 4 <= cnt; k += 4){
            int s0 = __shfl(my_s, k+0), s1 = __shfl(my_s, k+1);
            int s2 = __shfl(my_s, k+2), s3 = __shfl(my_s, k+3);
            float w0 = __shfl(my_e, k+0), w1 = __shfl(my_e, k+1);
            float w2 = __shfl(my_e, k+2), w3 = __shfl(my_e, k+3);
            float h0 = __half2float(H[(size_t)s0 * D + lane]);
            float h1 = __half2float(H[(size_t)s1 * D + lane]);
            float h2 = __half2float(H[(size_t)s2 * D + lane]);
            float h3 = __half2float(H[(size_t)s3 * D + lane]);
            c0 = fmaf(h0, w0, c0); c1 = fmaf(h1, w1, c1);
            c2 = fmaf(h2, w2, c2); c3 = fmaf(h3, w3, c3);
          }
          for (; k < cnt; ++k){
            int s0 = __shfl(my_s, k);
            float w0 = __shfl(my_e, k);
            c0 = fmaf(__half2float(H[(size_t)s0 * D + lane]), w0, c0);
          }
        }
        #pragma unroll
        for (int off = 32; off; off >>= 1) ss += __shfl_xor(ss, off);
        float inv = 1.f / (ss + 1e-16f);
        float acc = (c0 + c1) + (c2 + c3);
        float r = acc * inv + bv;
        if (relu) r = fmaxf(r, 0.f);
        out[(size_t)vv * D + lane] = r;
      }
    }
  }
}

extern "C" void kernel_launch(void* const* d_in, const int* in_sizes, int n_in,
                              void* d_out, int out_size, void* d_ws, size_t ws_size,
                              hipStream_t stream)
{
  const float* x    = (const float*)d_in[0];
  const int*   ei   = (const int*)d_in[1];    // integer inputs arrive as int32
  const float* ea   = (const float*)d_in[2];
  const float* W1   = (const float*)d_in[3];
  const float* We1  = (const float*)d_in[4];
  const float* as1  = (const float*)d_in[5];
  const float* ad1  = (const float*)d_in[6];
  const float* ae1  = (const float*)d_in[7];
  const float* b1   = (const float*)d_in[8];
  const float* W2   = (const float*)d_in[9];
  const float* We2  = (const float*)d_in[10];
  const float* as2  = (const float*)d_in[11];
  const float* ad2  = (const float*)d_in[12];
  const float* ae2  = (const float*)d_in[13];
  const float* b2   = (const float*)d_in[14];
  float* out = (float*)d_out;

  int n = in_sizes[0] / D;     // 100000
  int e = in_sizes[1] / 2;     // 1600000
  const int* srcp = ei;
  const int* dstp = ei + e;

  int nbkt   = (n + NPB - 1) / NPB;          // 196
  int nchunk = (e + PCHUNK - 1) / PCHUNK;    // 391  (must be <= 512)

  char* p = (char*)d_ws;
  __half* buf_h  = (__half*)p; p += (size_t)n * D * 2;   // fp16 H
  float* buf_x2  = (float*)p;  p += (size_t)n * D * 4;
  float* asrc    = (float*)p;  p += (size_t)n * 4;
  float* adst    = (float*)p;  p += (size_t)n * 4;
  int*   rowptr  = (int*)p;    p += (size_t)(n + 16) * 4;
  int*   gbase   = (int*)p;    p += (size_t)(nbkt + 4) * 4;
  int*   btot    = (int*)p;    p += (size_t)(nbkt + 4) * 4;
  int*   C       = (int*)p;    p += (size_t)nbkt * nchunk * 4;
  float* ce      = (float*)p;  p += 64;
  int2*  edges   = (int2*)p;   p += (size_t)e * 8;
  // staging aliases buf_x2: consumed by k_bucket before layer-1 writes buf_x2
  int2*  staging = (int2*)buf_x2;

  int pairs = (n + 1) / 2;
  int gR = (pairs + 3) / 4;         // wave per 2 nodes, 4 waves per block
  int gG = ((n + 7) / 8 + 3) / 4;   // gemm: one 8-row group per wave

  // ---- CSR build (contention-free radix partition) ----
  k_ce<<<1, 64, 0, stream>>>(We1, ae1, We2, ae2, ce);
  k_bhist<<<nchunk, 256, 0, stream>>>(dstp, C, nchunk, e, nbkt);
  k_cscan<<<nbkt, 512, 0, stream>>>(C, btot, nchunk);
  k_bscan<<<1, 256, 0, stream>>>(btot, gbase, nbkt);
  k_part<<<nchunk, 256, 0, stream>>>(srcp, dstp, ea, gbase, C, nchunk, staging, e, nbkt);
  k_bucket<<<nbkt, NPB, 0, stream>>>(gbase, staging, edges, rowptr, n, nbkt);

  // ---- layer 1 ----
  k_gemm_dots<<<gG, 256, 0, stream>>>(x, W1, as1, ad1, buf_h, asrc, adst, n);
  k_node_fused<<<gR, 256, 0, stream>>>(rowptr, edges, asrc, adst, ce, 0, buf_h, b1, buf_x2, n, 1);

  // ---- layer 2 ----
  k_gemm_dots<<<gG, 256, 0, stream>>>(buf_x2, W2, as2, ad2, buf_h, asrc, adst, n);
  k_node_fused<<<gR, 256, 0, stream>>>(rowptr, edges, asrc, adst, ce, 1, buf_h, b2, out, n, 0);
}